// Round 5
// baseline (199.987 us; speedup 1.0000x reference)
//
#include <hip/hip_runtime.h>
#include <math.h>

#define B_   8
#define C_   256
#define NH_  8
#define N_   1024
#define LOG2E    1.4426950408889634f

typedef __attribute__((ext_vector_type(8))) short bf16x8;
typedef __attribute__((ext_vector_type(4))) float f32x4;
typedef unsigned short u16;
typedef unsigned int u32;

#define AS1 __attribute__((address_space(1)))
#define AS3 __attribute__((address_space(3)))

__device__ __forceinline__ f32x4 mfma16(bf16x8 a, bf16x8 b, f32x4 c) {
    return __builtin_amdgcn_mfma_f32_16x16x32_bf16(a, b, c, 0, 0, 0);
}
__device__ __forceinline__ u32 bf16r(float x) {     // RNE f32->bf16 bits
    u32 b = __float_as_uint(x);
    return (b + 0x7fffu + ((b >> 16) & 1u)) >> 16;
}
// exact algebra: tanh(softplus(x)) = (e^2+2e)/(e^2+2e+2), e = exp(x)
__device__ __forceinline__ float mish_fast(float x) {
    float e  = __builtin_amdgcn_exp2f(fminf(x, 30.f) * LOG2E);
    float nm = e * (e + 2.f);
    return x * nm * __builtin_amdgcn_rcpf(nm + 2.f);
}
// deg-11 truncated Chebyshev of f(c)=e^{1-acos(c)/pi}; coefficients from the
// exact integrals a_n = (2e/pi)*(-1/pi)*((-1)^n/e - 1)/(1/pi^2 + n^2).
// Interior |err| <~ 3e-3 abs; edges (|c|->1) deficit ~0.05/0.016 (negligible-
// weight entries). Both sweeps share it, so P/rowsum systematics cancel.
__device__ __forceinline__ float fexp_poly(float c) {
    c = __builtin_amdgcn_fmed3f(c, -0.999999f, 0.999999f);
    float r = fmaf(6.3713280f, c, 1.7809920f);
    r = fmaf(r, c, -15.1427584f);
    r = fmaf(r, c, -3.7571968f);
    r = fmaf(r, c, 13.1518784f);
    r = fmaf(r, c, 2.8140000f);
    r = fmaf(r, c, -4.8903712f);
    r = fmaf(r, c, -0.8122592f);
    r = fmaf(r, c, 0.8441120f);
    r = fmaf(r, c, 0.1705120f);
    r = fmaf(r, c, 0.4936541f);
    r = fmaf(r, c, 1.6473155f);
    return r;
}

// ---------- Kernel 1: fused grouped conv + BN + mish + normalize + pack ----
// Block = (b, g, 256-col n-tile). Thread owns one n: all 32 channels of
// q,k,v computed from x held in registers; weights come in as SGPR loads.
// Outputs: qpk/kpk rows [bh][n][32 bf16] (64B, unit-normalized), vbf [bh][d][n].
__global__ __launch_bounds__(256) void qkvpack_kernel(
    const float* __restrict__ x,
    const float* __restrict__ qw, const float* __restrict__ qb2,
    const float* __restrict__ qs, const float* __restrict__ qbeta,
    const float* __restrict__ kw, const float* __restrict__ kb2,
    const float* __restrict__ ks, const float* __restrict__ kbeta,
    const float* __restrict__ vw, const float* __restrict__ vb2,
    const float* __restrict__ vs, const float* __restrict__ vbeta,
    uint4* __restrict__ qpk, uint4* __restrict__ kpk, u16* __restrict__ vbf)
{
    int blk = blockIdx.x;                 // b*32 + g*4 + nt
    int nt = blk & 3, g = (blk >> 2) & 7, b = blk >> 5;
    int n = nt * 256 + threadIdx.x;
    int bh = b * 8 + g;
    const float* xp = x + ((size_t)b * C_ + g * 32) * N_ + n;
    float xv[32];
#pragma unroll
    for (int i = 0; i < 32; ++i) xv[i] = xp[(size_t)i * N_];

    float yq[32], yk[32];
#pragma unroll
    for (int co = 0; co < 32; ++co) {
        int cg = g * 32 + co;
        float aq = 0.f, ak = 0.f, av = 0.f;
#pragma unroll
        for (int i = 0; i < 32; ++i) {
            aq = fmaf(xv[i], qw[cg * 32 + i], aq);
            ak = fmaf(xv[i], kw[cg * 32 + i], ak);
            av = fmaf(xv[i], vw[cg * 32 + i], av);
        }
        // INV_TEMP omitted: q normalized below, scale cancels in cosine
        yq[co] = mish_fast(qs[cg] * (aq + qb2[cg]) + qbeta[cg]);
        yk[co] = mish_fast(ks[cg] * (ak + kb2[cg]) + kbeta[cg]);
        float yv = mish_fast(vs[cg] * (av + vb2[cg]) + vbeta[cg]);
        vbf[((size_t)bh * 32 + co) * N_ + n] = (u16)bf16r(yv);
    }
    float sq = 0.f, sk = 0.f;
#pragma unroll
    for (int d = 0; d < 32; ++d) { sq = fmaf(yq[d], yq[d], sq); sk = fmaf(yk[d], yk[d], sk); }
    float iq = __builtin_amdgcn_rsqf(fmaxf(sq, 1e-24f));
    float ik = __builtin_amdgcn_rsqf(fmaxf(sk, 1e-24f));
    u32 wq[16], wk[16];
#pragma unroll
    for (int d = 0; d < 16; ++d) {
        wq[d] = bf16r(yq[2 * d] * iq) | (bf16r(yq[2 * d + 1] * iq) << 16);
        wk[d] = bf16r(yk[2 * d] * ik) | (bf16r(yk[2 * d + 1] * ik) << 16);
    }
    uint4* qd = qpk + ((size_t)bh * N_ + n) * 4;
    uint4* kd = kpk + ((size_t)bh * N_ + n) * 4;
#pragma unroll
    for (int j = 0; j < 4; ++j) {
        qd[j] = make_uint4(wq[4 * j], wq[4 * j + 1], wq[4 * j + 2], wq[4 * j + 3]);
        kd[j] = make_uint4(wk[4 * j], wk[4 * j + 1], wk[4 * j + 2], wk[4 * j + 3]);
    }
}

// ---------------- Kernel 1c: f_w -> bf16 -----------------------------------
__global__ __launch_bounds__(256) void wcvt_kernel(
    const float* __restrict__ fw, u16* __restrict__ wbf)
{
    int id = blockIdx.x * 1024 + threadIdx.x;
#pragma unroll
    for (int j = 0; j < 4; ++j) { int p = id + j * 256; wbf[p] = (u16)bf16r(fw[p]); }
}

// ---------------- Kernel 2: attention (K/V LDS-resident, poly softmax) -----
// Block = (bh, quarter of q-rows = 256). K (64KB) + V (64KB) staged once.
// Sweep 1: rowsums for all 4 q-tiles. Sweep 2: P (raw), am, PV; rinv deferred.
#define SMEM_V  65536
#define SMEM_P  131072
#define SMEM_AM (131072 + 17408)
#define SMEM_BYTES (SMEM_AM + 4096)

__global__ __launch_bounds__(256) void attn_kernel(
    const u16* __restrict__ qpk, const u16* __restrict__ kpk,
    const u16* __restrict__ vbf,
    u16* __restrict__ aout_bt, float* __restrict__ ampart)
{
    extern __shared__ __align__(16) char smem[];
    u16*   Ps  = (u16*)(smem + SMEM_P);     // [4 waves][16 rows x 272B]
    float* amW = (float*)(smem + SMEM_AM);  // [1024]

    const int tid  = threadIdx.x;
    const int wave = tid >> 6, lane = tid & 63;
    const int l15 = lane & 15, lg = lane >> 4;
    const int blk = blockIdx.x;             // bh*4 + qq
    const int qq = blk & 3, bh = blk >> 2;
    const int h = bh & 7, bidx = bh >> 3;
    const int n00 = qq * 256;

    const char* ksrc = (const char*)(kpk + (size_t)bh * N_ * 32);
    const char* vsrc = (const char*)(vbf + (size_t)bh * 32 * N_);
    const char* qsrc = (const char*)(qpk + (size_t)bh * N_ * 32);

    // ---- stage K: LDS layout Kl[j=dchunk][m][8 bf16], granule gi=j*1024+m ----
#pragma unroll
    for (int p = 0; p < 16; ++p) {
        int gi = p * 256 + wave * 64 + lane;
        int j = gi >> 10, m = gi & 1023;
        __builtin_amdgcn_global_load_lds(
            (const AS1 void*)(ksrc + m * 64 + j * 16),
            (AS3 void*)(smem + ((p * 256 + wave * 64) << 4)), 16, 0, 0);
    }
    // ---- stage V: Vl[d][m] rows 2KB, granule-XOR key (d&7), src pre-swizzled
#pragma unroll
    for (int p = 0; p < 16; ++p) {
        int gi = p * 256 + wave * 64 + lane;
        int d = gi >> 7, gm = gi & 127;
        __builtin_amdgcn_global_load_lds(
            (const AS1 void*)(vsrc + d * 2048 + ((gm ^ (d & 7)) << 4)),
            (AS3 void*)(smem + SMEM_V + ((p * 256 + wave * 64) << 4)), 16, 0, 0);
    }
#pragma unroll
    for (int j2 = 0; j2 < 4; ++j2) amW[tid + 256 * j2] = 0.f;
    asm volatile("s_waitcnt lgkmcnt(0)" ::: "memory");
    asm volatile("s_waitcnt vmcnt(16)" ::: "memory");   // K granules landed
    __builtin_amdgcn_s_barrier();

    // per-lane K frag base: row m = t*16 + l15, d-chunk lg
    const char* kfb = smem + (lg << 14) + (l15 << 4);

    // ================= sweep 1: rowsums (poly, no normalization) ===========
    float rinv[4][4];
#pragma unroll
    for (int qt = 0; qt < 4; ++qt) {
        int i = n00 + qt * 64 + wave * 16 + l15;
        bf16x8 aq = *(const bf16x8*)(qsrc + (size_t)i * 64 + lg * 16);
        float rs[4] = {0.f, 0.f, 0.f, 0.f};
#pragma unroll 8
        for (int t = 0; t < 64; ++t) {
            bf16x8 bk = *(const bf16x8*)(kfb + t * 256);
            f32x4 cf = {0.f, 0.f, 0.f, 0.f};
            cf = mfma16(aq, bk, cf);
#pragma unroll
            for (int r = 0; r < 4; ++r) rs[r] += fexp_poly(cf[r]);
        }
#pragma unroll
        for (int r = 0; r < 4; ++r) {
            float s = rs[r];
            s += __shfl_xor(s, 1); s += __shfl_xor(s, 2);
            s += __shfl_xor(s, 4); s += __shfl_xor(s, 8);
            rinv[qt][r] = __builtin_amdgcn_rcpf(s);
        }
    }
    asm volatile("s_waitcnt vmcnt(0)" ::: "memory");    // V granules landed
    __builtin_amdgcn_s_barrier();

    // ================= sweep 2: P(raw), am, PV =============================
    char*       psw = (char*)Ps + wave * 4352 + lg * 1088 + l15 * 2;
    const char* pab = (const char*)Ps + wave * 4352 + l15 * 272 + lg * 16;
    const char* vfb = smem + SMEM_V + (l15 << 11);
    const int   vkey = l15 & 7;

#pragma unroll
    for (int qt = 0; qt < 4; ++qt) {
        int i = n00 + qt * 64 + wave * 16 + l15;
        bf16x8 aq = *(const bf16x8*)(qsrc + (size_t)i * 64 + lg * 16);
        f32x4 o0 = {0.f, 0.f, 0.f, 0.f}, o1 = {0.f, 0.f, 0.f, 0.f};
        for (int ch = 0; ch < 8; ++ch) {
#pragma unroll
            for (int t = 0; t < 8; ++t) {
                bf16x8 bk = *(const bf16x8*)(kfb + (ch * 8 + t) * 256);
                f32x4 cf = {0.f, 0.f, 0.f, 0.f};
                cf = mfma16(aq, bk, cf);
                float csum = 0.f;
#pragma unroll
                for (int r = 0; r < 4; ++r) {
                    float f = fexp_poly(cf[r]);
                    csum = fmaf(f, rinv[qt][r], csum);
                    *(u16*)(psw + r * 272 + t * 32) = (u16)bf16r(f);
                }
                csum += __shfl_xor(csum, 16);
                csum += __shfl_xor(csum, 32);
                if (lane < 16) atomicAdd(&amW[ch * 128 + t * 16 + l15], csum);
            }
            asm volatile("s_waitcnt lgkmcnt(0)" ::: "memory");
            __builtin_amdgcn_sched_barrier(0);
#pragma unroll
            for (int kss = 0; kss < 4; ++kss) {
                bf16x8 pa = *(const bf16x8*)(pab + kss * 64);
                int g = ch * 16 + kss * 4 + lg;
                const char* va = vfb + ((g ^ vkey) << 4);
                bf16x8 v0 = *(const bf16x8*)va;
                bf16x8 v1 = *(const bf16x8*)(va + 32768);
                o0 = mfma16(pa, v0, o0);
                o1 = mfma16(pa, v1, o1);
            }
        }
        // ---- epilogue qt: scale by rinv, transpose via LDS (reuse Ps) ----
        __syncthreads();
        {
            u16* oT = (u16*)Ps;                    // [64 rows][40 u16]
#pragma unroll
            for (int r = 0; r < 4; ++r) {
                int irow = wave * 16 + lg * 4 + r;
                oT[irow * 40 + l15]      = (u16)bf16r(o0[r] * rinv[qt][r]);
                oT[irow * 40 + 16 + l15] = (u16)bf16r(o1[r] * rinv[qt][r]);
            }
        }
        __syncthreads();
        {
            const u16* oT = (const u16*)Ps;
            int row = tid >> 2, c4 = tid & 3;
            uint4 val = *(const uint4*)((const char*)oT + row * 80 + c4 * 16);
            int n = n00 + qt * 64 + row;
            int g = h * 4 + c4;
            size_t dst = ((size_t)(bidx * N_ + n) << 9) + ((size_t)((g ^ (row & 7)) << 4));
            *(uint4*)((char*)aout_bt + dst) = val;
        }
        __syncthreads();
    }
#pragma unroll
    for (int j2 = 0; j2 < 4; ++j2)
        ampart[(size_t)blk * N_ + tid + 256 * j2] = amW[tid + 256 * j2];
}

// ---------------- Kernel 3: attention-map reduce + min/max normalize -------
__global__ __launch_bounds__(256) void am_kernel(
    const float* __restrict__ amp, float* __restrict__ outAm)
{
    int b = blockIdx.x, tid = threadIdx.x;
    const float* base = amp + (size_t)b * 32 * N_;
    float s[4] = {0.f, 0.f, 0.f, 0.f};
    for (int p = 0; p < 32; ++p) {
#pragma unroll
        for (int c2 = 0; c2 < 4; ++c2)
            s[c2] += base[(size_t)p * N_ + tid + 256 * c2];
    }
    float mn = fminf(fminf(s[0], s[1]), fminf(s[2], s[3]));
    float mx = fmaxf(fmaxf(s[0], s[1]), fmaxf(s[2], s[3]));
    __shared__ float rmn[256], rmx[256];
    rmn[tid] = mn; rmx[tid] = mx;
    __syncthreads();
    for (int off = 128; off >= 1; off >>= 1) {
        if (tid < off) {
            rmn[tid] = fminf(rmn[tid], rmn[tid + off]);
            rmx[tid] = fmaxf(rmx[tid], rmx[tid + off]);
        }
        __syncthreads();
    }
    mn = rmn[0]; mx = rmx[0];
    float inv = 1.f / (mx - mn);
#pragma unroll
    for (int c2 = 0; c2 < 4; ++c2)
        outAm[(size_t)b * N_ + tid + 256 * c2] = (s[c2] - mn) * inv;
}

// ---------------- Kernel 4: final 1x1 conv (MFMA) + mish + residual --------
__global__ __launch_bounds__(256) void fconv_kernel(
    const u16* __restrict__ aout_bt, const u16* __restrict__ wbf,
    const float* __restrict__ x,
    const float* __restrict__ fs, const float* __restrict__ fb,
    const float* __restrict__ fbeta, float* __restrict__ y)
{
    __shared__ __align__(16) u16 As[32 * 256];   // 16 KB [n][c] swizzled
    const int tid  = threadIdx.x;
    const int wave = tid >> 6, lane = tid & 63;
    const int l15 = lane & 15, lg = lane >> 4;
    const int b  = blockIdx.x >> 5;
    const int n0 = (blockIdx.x & 31) * 32;

    const char* asrc = (const char*)aout_bt + ((size_t)(b * N_ + n0) << 9);
#pragma unroll
    for (int p = 0; p < 4; ++p) {
        int g = p * 256 + wave * 64 + lane;
        __builtin_amdgcn_global_load_lds(
            (const AS1 void*)(asrc + g * 16),
            (AS3 void*)((char*)As + ((p * 256 + wave * 64) << 4)), 16, 0, 0);
    }
    __syncthreads();

    f32x4 acc[4][2];
#pragma unroll
    for (int f = 0; f < 4; ++f)
#pragma unroll
        for (int fn = 0; fn < 2; ++fn) acc[f][fn] = (f32x4){0.f, 0.f, 0.f, 0.f};

    const int cobase = wave * 64;
#pragma unroll
    for (int kk = 0; kk < 8; ++kk) {
        bf16x8 af[2];
#pragma unroll
        for (int fn = 0; fn < 2; ++fn) {
            int nf = fn * 16 + l15;
            af[fn] = *(const bf16x8*)((const char*)As + nf * 512 +
                                      (((kk * 4 + lg) ^ (nf & 7)) << 4));
        }
#pragma unroll
        for (int f = 0; f < 4; ++f) {
            bf16x8 wf = *(const bf16x8*)(wbf + (size_t)(cobase + f * 16 + l15) * 256 + kk * 32 + lg * 8);
            acc[f][0] = mfma16(wf, af[0], acc[f][0]);
            acc[f][1] = mfma16(wf, af[1], acc[f][1]);
        }
    }

#pragma unroll
    for (int f = 0; f < 4; ++f) {
#pragma unroll
        for (int r = 0; r < 4; ++r) {
            int co = cobase + f * 16 + lg * 4 + r;
            float sc = fs[co], bb = fb[co], bt = fbeta[co];
#pragma unroll
            for (int fn = 0; fn < 2; ++fn) {
                int n = n0 + fn * 16 + l15;
                size_t oid = ((size_t)(b * C_ + co) << 10) + n;
                y[oid] = mish_fast(sc * (acc[f][fn][r] + bb) + bt) + x[oid];
            }
        }
    }
}

extern "C" void kernel_launch(void* const* d_in, const int* in_sizes, int n_in,
                              void* d_out, int out_size, void* d_ws, size_t ws_size,
                              hipStream_t stream)
{
    const float* x     = (const float*)d_in[0];
    const float* q_w   = (const float*)d_in[1];
    const float* q_b   = (const float*)d_in[2];
    const float* q_s   = (const float*)d_in[3];
    const float* q_be  = (const float*)d_in[4];
    const float* k_w   = (const float*)d_in[5];
    const float* k_b   = (const float*)d_in[6];
    const float* k_s   = (const float*)d_in[7];
    const float* k_be  = (const float*)d_in[8];
    const float* v_w   = (const float*)d_in[9];
    const float* v_b   = (const float*)d_in[10];
    const float* v_s   = (const float*)d_in[11];
    const float* v_be  = (const float*)d_in[12];
    const float* f_w   = (const float*)d_in[13];
    const float* f_b   = (const float*)d_in[14];
    const float* f_s   = (const float*)d_in[15];
    const float* f_be  = (const float*)d_in[16];

    float* y_out  = (float*)d_out;                        // (8,256,32,32)
    float* am_out = (float*)d_out + (size_t)B_ * C_ * N_; // (8,32,32)

    char* w = (char*)d_ws;
    u16*   qpk     = (u16*)w;    w += (size_t)B_ * NH_ * N_ * 64;    // 4 MB
    u16*   kpk     = (u16*)w;    w += (size_t)B_ * NH_ * N_ * 64;    // 4 MB
    u16*   vbf     = (u16*)w;    w += (size_t)B_ * C_ * N_ * 2;      // 4 MB
    u16*   aout_bt = (u16*)w;    w += (size_t)B_ * N_ * C_ * 2;      // 4 MB
    float* ampart  = (float*)w;  w += (size_t)B_ * NH_ * 4 * N_ * 4; // 1 MB
    u16*   wbf     = (u16*)w;                                        // 128 KB

    qkvpack_kernel<<<B_ * NH_ * 4, 256, 0, stream>>>(
        x, q_w, q_b, q_s, q_be, k_w, k_b, k_s, k_be,
        v_w, v_b, v_s, v_be, (uint4*)qpk, (uint4*)kpk, vbf);

    wcvt_kernel<<<64, 256, 0, stream>>>(f_w, wbf);

    hipFuncSetAttribute((const void*)attn_kernel,
                        hipFuncAttributeMaxDynamicSharedMemorySize, SMEM_BYTES);
    attn_kernel<<<B_ * NH_ * 4, 256, SMEM_BYTES, stream>>>(
        qpk, kpk, vbf, aout_bt, ampart);

    am_kernel<<<B_, 256, 0, stream>>>(ampart, am_out);

    fconv_kernel<<<B_ * 32, 256, 0, stream>>>(
        aout_bt, wbf, x, f_s, f_b, f_be, y_out);
}

// Round 6
// 145.475 us; speedup vs baseline: 1.3747x; 1.3747x over previous
//
#include <hip/hip_runtime.h>
#include <math.h>

#define B_   8
#define C_   256
#define NH_  8
#define N_   1024
#define LOG2E    1.4426950408889634f

typedef __attribute__((ext_vector_type(8))) short bf16x8;
typedef __attribute__((ext_vector_type(4))) float f32x4;
typedef unsigned short u16;
typedef unsigned int u32;

#define AS1 __attribute__((address_space(1)))
#define AS3 __attribute__((address_space(3)))

__device__ __forceinline__ f32x4 mfma16(bf16x8 a, bf16x8 b, f32x4 c) {
    return __builtin_amdgcn_mfma_f32_16x16x32_bf16(a, b, c, 0, 0, 0);
}
__device__ __forceinline__ u32 bf16r(float x) {     // RNE f32->bf16 bits
    u32 b = __float_as_uint(x);
    return (b + 0x7fffu + ((b >> 16) & 1u)) >> 16;
}
// exact algebra: tanh(softplus(x)) = (e^2+2e)/(e^2+2e+2), e = exp(x)
__device__ __forceinline__ float mish_fast(float x) {
    float e  = __builtin_amdgcn_exp2f(fminf(x, 30.f) * LOG2E);
    float nm = e * (e + 2.f);
    return x * nm * __builtin_amdgcn_rcpf(nm + 2.f);
}
// deg-11 truncated Chebyshev of f(c)=e^{1-acos(c)/pi}; both sweeps share it,
// so P/rowsum systematics cancel. Interior |err| <~ 3e-3 abs.
__device__ __forceinline__ float fexp_poly(float c) {
    c = __builtin_amdgcn_fmed3f(c, -0.999999f, 0.999999f);
    float r = fmaf(6.3713280f, c, 1.7809920f);
    r = fmaf(r, c, -15.1427584f);
    r = fmaf(r, c, -3.7571968f);
    r = fmaf(r, c, 13.1518784f);
    r = fmaf(r, c, 2.8140000f);
    r = fmaf(r, c, -4.8903712f);
    r = fmaf(r, c, -0.8122592f);
    r = fmaf(r, c, 0.8441120f);
    r = fmaf(r, c, 0.1705120f);
    r = fmaf(r, c, 0.4936541f);
    r = fmaf(r, c, 1.6473155f);
    return r;
}

// ---------- Kernel 1: fused grouped conv + BN + mish + normalize + pack ----
// blocks 0..255: qkv. blocks 256..319: f_w -> bf16 convert.
__global__ __launch_bounds__(256) void qkvpack_kernel(
    const float* __restrict__ x,
    const float* __restrict__ qw, const float* __restrict__ qb2,
    const float* __restrict__ qs, const float* __restrict__ qbeta,
    const float* __restrict__ kw, const float* __restrict__ kb2,
    const float* __restrict__ ks, const float* __restrict__ kbeta,
    const float* __restrict__ vw, const float* __restrict__ vb2,
    const float* __restrict__ vs, const float* __restrict__ vbeta,
    uint4* __restrict__ qpk, uint4* __restrict__ kpk, u16* __restrict__ vbf,
    const float* __restrict__ fw, u16* __restrict__ wbf)
{
    int blk = blockIdx.x;
    if (blk >= 256) {               // f_w -> bf16
        int id = (blk - 256) * 1024 + threadIdx.x;
#pragma unroll
        for (int j = 0; j < 4; ++j) { int p = id + j * 256; wbf[p] = (u16)bf16r(fw[p]); }
        return;
    }
    int nt = blk & 3, g = (blk >> 2) & 7, b = blk >> 5;   // b*32 + g*4 + nt
    int n = nt * 256 + threadIdx.x;
    int bh = b * 8 + g;
    const float* xp = x + ((size_t)b * C_ + g * 32) * N_ + n;
    float xv[32];
#pragma unroll
    for (int i = 0; i < 32; ++i) xv[i] = xp[(size_t)i * N_];

    float yq[32], yk[32];
#pragma unroll
    for (int co = 0; co < 32; ++co) {
        int cg = g * 32 + co;
        float aq = 0.f, ak = 0.f, av = 0.f;
#pragma unroll
        for (int i = 0; i < 32; ++i) {
            aq = fmaf(xv[i], qw[cg * 32 + i], aq);
            ak = fmaf(xv[i], kw[cg * 32 + i], ak);
            av = fmaf(xv[i], vw[cg * 32 + i], av);
        }
        // INV_TEMP omitted: q normalized below, scale cancels in cosine
        yq[co] = mish_fast(qs[cg] * (aq + qb2[cg]) + qbeta[cg]);
        yk[co] = mish_fast(ks[cg] * (ak + kb2[cg]) + kbeta[cg]);
        float yv = mish_fast(vs[cg] * (av + vb2[cg]) + vbeta[cg]);
        vbf[((size_t)bh * 32 + co) * N_ + n] = (u16)bf16r(yv);
    }
    float sq = 0.f, sk = 0.f;
#pragma unroll
    for (int d = 0; d < 32; ++d) { sq = fmaf(yq[d], yq[d], sq); sk = fmaf(yk[d], yk[d], sk); }
    float iq = __builtin_amdgcn_rsqf(fmaxf(sq, 1e-24f));
    float ik = __builtin_amdgcn_rsqf(fmaxf(sk, 1e-24f));
    u32 wq[16], wk[16];
#pragma unroll
    for (int d = 0; d < 16; ++d) {
        wq[d] = bf16r(yq[2 * d] * iq) | (bf16r(yq[2 * d + 1] * iq) << 16);
        wk[d] = bf16r(yk[2 * d] * ik) | (bf16r(yk[2 * d + 1] * ik) << 16);
    }
    uint4* qd = qpk + ((size_t)bh * N_ + n) * 4;
    uint4* kd = kpk + ((size_t)bh * N_ + n) * 4;
#pragma unroll
    for (int j = 0; j < 4; ++j) {
        qd[j] = make_uint4(wq[4 * j], wq[4 * j + 1], wq[4 * j + 2], wq[4 * j + 3]);
        kd[j] = make_uint4(wk[4 * j], wk[4 * j + 1], wk[4 * j + 2], wk[4 * j + 3]);
    }
}

// ---------------- Kernel 2: attention (chunked, poly softmax, 1 MFMA) ------
// Block = (bh, 64-row itile), 4 waves x 16 rows. m in 8 chunks of 128.
// 37 KB LDS -> 4 blocks/CU. Q frag in regs; K/V staged per chunk via
// global_load_lds. Sweep 1: rowsums. Sweep 2: P(raw), am, PV; rinv deferred.
__global__ __launch_bounds__(256) void attn_kernel(
    const u16* __restrict__ qpk, const u16* __restrict__ kpk,
    const u16* __restrict__ vbf,
    u16* __restrict__ aout_bt, float* __restrict__ ampart)
{
    __shared__ __align__(16) u16 Kc[4][128][8];     // 8 KB  [dchunk][m][8]
    __shared__ __align__(16) u16 Vc[32][128];       // 8 KB  [d][m] granule-swz
    __shared__ __align__(16) u16 Ps[4][16 * 136];   // 17 KB, rows padded 272B
    __shared__ __align__(16) float amW[N_];         // 4 KB

    const int tid  = threadIdx.x;
    const int wave = tid >> 6, lane = tid & 63;
    const int l15 = lane & 15, lg = lane >> 4;
    const int blk = blockIdx.x;             // bh*16 + itile
    const int itile = blk & 15, bh = blk >> 4;
    const int h = bh & 7, bidx = bh >> 3;
    const int i0 = itile * 64;

    const char* ksrc = (const char*)(kpk + (size_t)bh * N_ * 32);
    const char* vsrc = (const char*)(vbf + (size_t)bh * 32 * N_);
    const char* qsrc = (const char*)(qpk + (size_t)bh * N_ * 32);

    for (int j = tid; j < N_; j += 256) amW[j] = 0.f;

    // Q frag: row = i0 + wave*16 + l15, d-chunk lg (held for whole kernel)
    bf16x8 aq = *(const bf16x8*)(qsrc + (size_t)(i0 + wave * 16 + l15) * 64 + lg * 16);

    const char* kfb = (const char*)Kc + lg * 2048 + l15 * 16;

    // ================= sweep 1: rowsums =================
    float rs[4] = {0.f, 0.f, 0.f, 0.f};
    for (int ch = 0; ch < 8; ++ch) {
        int m0 = ch * 128;
        __syncthreads();
#pragma unroll
        for (int p = 0; p < 2; ++p) {
            int gi = p * 256 + wave * 64 + lane;
            int j = gi >> 7, m = gi & 127;
            __builtin_amdgcn_global_load_lds(
                (const AS1 void*)(ksrc + (size_t)(m0 + m) * 64 + j * 16),
                (AS3 void*)((char*)Kc + ((p * 256 + wave * 64) << 4)), 16, 0, 0);
        }
        __syncthreads();
#pragma unroll
        for (int t = 0; t < 8; ++t) {
            bf16x8 bk = *(const bf16x8*)(kfb + t * 256);
            f32x4 cf = {0.f, 0.f, 0.f, 0.f};
            cf = mfma16(aq, bk, cf);
#pragma unroll
            for (int r = 0; r < 4; ++r) rs[r] += fexp_poly(cf[r]);
        }
    }
    float rinv[4];
#pragma unroll
    for (int r = 0; r < 4; ++r) {
        float s = rs[r];
        s += __shfl_xor(s, 1); s += __shfl_xor(s, 2);
        s += __shfl_xor(s, 4); s += __shfl_xor(s, 8);
        rinv[r] = __builtin_amdgcn_rcpf(s);
    }

    // ================= sweep 2: P(raw), am, PV =================
    f32x4 o0 = {0.f, 0.f, 0.f, 0.f}, o1 = {0.f, 0.f, 0.f, 0.f};
    char*       psw = (char*)&Ps[wave][0] + lg * 1088 + l15 * 2;
    const char* pab = (const char*)&Ps[wave][0] + l15 * 272 + lg * 16;
    const char* vfb = (const char*)Vc + l15 * 256;
    const int   vkey = l15 & 7;

    for (int ch = 0; ch < 8; ++ch) {
        int m0 = ch * 128;
        __syncthreads();
#pragma unroll
        for (int p = 0; p < 2; ++p) {
            int gi = p * 256 + wave * 64 + lane;
            int j = gi >> 7, m = gi & 127;
            __builtin_amdgcn_global_load_lds(
                (const AS1 void*)(ksrc + (size_t)(m0 + m) * 64 + j * 16),
                (AS3 void*)((char*)Kc + ((p * 256 + wave * 64) << 4)), 16, 0, 0);
        }
#pragma unroll
        for (int p = 0; p < 2; ++p) {
            int gi = p * 256 + wave * 64 + lane;
            int d = gi >> 4, gm = gi & 15;
            __builtin_amdgcn_global_load_lds(
                (const AS1 void*)(vsrc + (size_t)d * 2048 + m0 * 2 + ((gm ^ (d & 7)) << 4)),
                (AS3 void*)((char*)Vc + ((p * 256 + wave * 64) << 4)), 16, 0, 0);
        }
        __syncthreads();

#pragma unroll
        for (int t = 0; t < 8; ++t) {
            bf16x8 bk = *(const bf16x8*)(kfb + t * 256);
            f32x4 cf = {0.f, 0.f, 0.f, 0.f};
            cf = mfma16(aq, bk, cf);
            float csum = 0.f;
#pragma unroll
            for (int r = 0; r < 4; ++r) {
                float f = fexp_poly(cf[r]);
                csum = fmaf(f, rinv[r], csum);
                *(u16*)(psw + r * 272 + t * 32) = (u16)bf16r(f);
            }
            csum += __shfl_xor(csum, 16);
            csum += __shfl_xor(csum, 32);
            if (lane < 16) atomicAdd(&amW[m0 + t * 16 + l15], csum);
        }
        asm volatile("s_waitcnt lgkmcnt(0)" ::: "memory");
        __builtin_amdgcn_sched_barrier(0);
#pragma unroll
        for (int kss = 0; kss < 4; ++kss) {
            bf16x8 pa = *(const bf16x8*)(pab + kss * 64);
            const char* va = vfb + (((kss * 4 + lg) ^ vkey) << 4);
            bf16x8 v0 = *(const bf16x8*)va;
            bf16x8 v1 = *(const bf16x8*)(va + 4096);      // d = 16 + l15
            o0 = mfma16(pa, v0, o0);
            o1 = mfma16(pa, v1, o1);
        }
    }
    __syncthreads();   // amW atomics done; Ps free for reuse

    // ---- epilogue: scale by rinv, transpose via LDS, store bf16 [b][n][c] ----
    {
        u16* oT = (u16*)Ps;                    // [64 rows][40 u16] (80B rows)
#pragma unroll
        for (int r = 0; r < 4; ++r) {
            int irow = wave * 16 + lg * 4 + r;
            oT[irow * 40 + l15]      = (u16)bf16r(o0[r] * rinv[r]);
            oT[irow * 40 + 16 + l15] = (u16)bf16r(o1[r] * rinv[r]);
        }
    }
    __syncthreads();
    {
        const u16* oT = (const u16*)Ps;
        int row = tid >> 2, c4 = tid & 3;
        uint4 val = *(const uint4*)((const char*)oT + row * 80 + c4 * 16);
        int n = i0 + row;
        int g = h * 4 + c4;
        size_t dst = ((size_t)(bidx * N_ + n) << 9) + ((size_t)((g ^ (row & 7)) << 4));
        *(uint4*)((char*)aout_bt + dst) = val;
    }
#pragma unroll
    for (int j2 = 0; j2 < 4; ++j2)
        ampart[(size_t)blk * N_ + tid + 256 * j2] = amW[tid + 256 * j2];
}

// ---------- Kernel 3: fconv (MFMA) + mish + residual; blocks 256..263: am --
__global__ __launch_bounds__(256) void fconv_kernel(
    const u16* __restrict__ aout_bt, const u16* __restrict__ wbf,
    const float* __restrict__ x,
    const float* __restrict__ fs, const float* __restrict__ fb,
    const float* __restrict__ fbeta, float* __restrict__ y,
    const float* __restrict__ ampart, float* __restrict__ outAm)
{
    __shared__ __align__(16) u16 As[32 * 256];   // 16 KB [n][c] swizzled
    __shared__ float rmn[256], rmx[256];
    const int tid = threadIdx.x;

    if (blockIdx.x >= 256) {       // ---- attention-map reduce + normalize ----
        int b = blockIdx.x - 256;
        const float* base = ampart + (size_t)b * 128 * N_;
        float s[4] = {0.f, 0.f, 0.f, 0.f};
        for (int p = 0; p < 128; ++p) {
#pragma unroll
            for (int c2 = 0; c2 < 4; ++c2)
                s[c2] += base[(size_t)p * N_ + tid + 256 * c2];
        }
        float mn = fminf(fminf(s[0], s[1]), fminf(s[2], s[3]));
        float mx = fmaxf(fmaxf(s[0], s[1]), fmaxf(s[2], s[3]));
        rmn[tid] = mn; rmx[tid] = mx;
        __syncthreads();
        for (int off = 128; off >= 1; off >>= 1) {
            if (tid < off) {
                rmn[tid] = fminf(rmn[tid], rmn[tid + off]);
                rmx[tid] = fmaxf(rmx[tid], rmx[tid + off]);
            }
            __syncthreads();
        }
        mn = rmn[0]; mx = rmx[0];
        float inv = 1.f / (mx - mn);
#pragma unroll
        for (int c2 = 0; c2 < 4; ++c2)
            outAm[(size_t)b * N_ + tid + 256 * c2] = (s[c2] - mn) * inv;
        return;
    }

    const int wave = tid >> 6, lane = tid & 63;
    const int l15 = lane & 15, lg = lane >> 4;
    const int b  = blockIdx.x >> 5;
    const int n0 = (blockIdx.x & 31) * 32;

    const char* asrc = (const char*)aout_bt + ((size_t)(b * N_ + n0) << 9);
#pragma unroll
    for (int p = 0; p < 4; ++p) {
        int g = p * 256 + wave * 64 + lane;
        __builtin_amdgcn_global_load_lds(
            (const AS1 void*)(asrc + g * 16),
            (AS3 void*)((char*)As + ((p * 256 + wave * 64) << 4)), 16, 0, 0);
    }
    __syncthreads();

    f32x4 acc[4][2];
#pragma unroll
    for (int f = 0; f < 4; ++f)
#pragma unroll
        for (int fn = 0; fn < 2; ++fn) acc[f][fn] = (f32x4){0.f, 0.f, 0.f, 0.f};

    const int cobase = wave * 64;
#pragma unroll
    for (int kk = 0; kk < 8; ++kk) {
        bf16x8 af[2];
#pragma unroll
        for (int fn = 0; fn < 2; ++fn) {
            int nf = fn * 16 + l15;
            af[fn] = *(const bf16x8*)((const char*)As + nf * 512 +
                                      (((kk * 4 + lg) ^ (nf & 7)) << 4));
        }
#pragma unroll
        for (int f = 0; f < 4; ++f) {
            bf16x8 wf = *(const bf16x8*)(wbf + (size_t)(cobase + f * 16 + l15) * 256 + kk * 32 + lg * 8);
            acc[f][0] = mfma16(wf, af[0], acc[f][0]);
            acc[f][1] = mfma16(wf, af[1], acc[f][1]);
        }
    }

#pragma unroll
    for (int f = 0; f < 4; ++f) {
#pragma unroll
        for (int r = 0; r < 4; ++r) {
            int co = cobase + f * 16 + lg * 4 + r;
            float sc = fs[co], bb = fb[co], bt = fbeta[co];
#pragma unroll
            for (int fn = 0; fn < 2; ++fn) {
                int n = n0 + fn * 16 + l15;
                size_t oid = ((size_t)(b * C_ + co) << 10) + n;
                y[oid] = mish_fast(sc * (acc[f][fn][r] + bb) + bt) + x[oid];
            }
        }
    }
}

extern "C" void kernel_launch(void* const* d_in, const int* in_sizes, int n_in,
                              void* d_out, int out_size, void* d_ws, size_t ws_size,
                              hipStream_t stream)
{
    const float* x     = (const float*)d_in[0];
    const float* q_w   = (const float*)d_in[1];
    const float* q_b   = (const float*)d_in[2];
    const float* q_s   = (const float*)d_in[3];
    const float* q_be  = (const float*)d_in[4];
    const float* k_w   = (const float*)d_in[5];
    const float* k_b   = (const float*)d_in[6];
    const float* k_s   = (const float*)d_in[7];
    const float* k_be  = (const float*)d_in[8];
    const float* v_w   = (const float*)d_in[9];
    const float* v_b   = (const float*)d_in[10];
    const float* v_s   = (const float*)d_in[11];
    const float* v_be  = (const float*)d_in[12];
    const float* f_w   = (const float*)d_in[13];
    const float* f_b   = (const float*)d_in[14];
    const float* f_s   = (const float*)d_in[15];
    const float* f_be  = (const float*)d_in[16];

    float* y_out  = (float*)d_out;                        // (8,256,32,32)
    float* am_out = (float*)d_out + (size_t)B_ * C_ * N_; // (8,32,32)

    char* w = (char*)d_ws;
    u16*   qpk     = (u16*)w;    w += (size_t)B_ * NH_ * N_ * 64;    // 4 MB
    u16*   kpk     = (u16*)w;    w += (size_t)B_ * NH_ * N_ * 64;    // 4 MB
    u16*   vbf     = (u16*)w;    w += (size_t)B_ * C_ * N_ * 2;      // 4 MB
    u16*   aout_bt = (u16*)w;    w += (size_t)B_ * N_ * C_ * 2;      // 4 MB
    float* ampart  = (float*)w;  w += (size_t)B_ * NH_ * 16 * N_ * 4;// 4 MB
    u16*   wbf     = (u16*)w;                                        // 128 KB

    qkvpack_kernel<<<320, 256, 0, stream>>>(
        x, q_w, q_b, q_s, q_be, k_w, k_b, k_s, k_be,
        v_w, v_b, v_s, v_be, (uint4*)qpk, (uint4*)kpk, vbf, f_w, wbf);

    attn_kernel<<<B_ * NH_ * 16, 256, 0, stream>>>(
        qpk, kpk, vbf, aout_bt, ampart);

    fconv_kernel<<<264, 256, 0, stream>>>(
        aout_bt, wbf, x, f_s, f_b, f_be, y_out, ampart, am_out);
}

// Round 7
// 107.308 us; speedup vs baseline: 1.8637x; 1.3557x over previous
//
#include <hip/hip_runtime.h>
#include <math.h>

#define B_   8
#define C_   256
#define NH_  8
#define N_   1024
#define LOG2E    1.4426950408889634f

typedef __attribute__((ext_vector_type(8))) short bf16x8;
typedef __attribute__((ext_vector_type(4))) float f32x4;
typedef __attribute__((ext_vector_type(2))) float f32x2;
typedef unsigned short u16;
typedef unsigned int u32;

#define AS1 __attribute__((address_space(1)))
#define AS3 __attribute__((address_space(3)))

__device__ __forceinline__ f32x4 mfma16(bf16x8 a, bf16x8 b, f32x4 c) {
    return __builtin_amdgcn_mfma_f32_16x16x32_bf16(a, b, c, 0, 0, 0);
}
__device__ __forceinline__ u32 bf16r(float x) {     // RNE f32->bf16 bits
    u32 b = __float_as_uint(x);
    return (b + 0x7fffu + ((b >> 16) & 1u)) >> 16;
}
// exact algebra: tanh(softplus(x)) = (e^2+2e)/(e^2+2e+2), e = exp(x)
__device__ __forceinline__ float mish_fast(float x) {
    float e  = __builtin_amdgcn_exp2f(fminf(x, 30.f) * LOG2E);
    float nm = e * (e + 2.f);
    return x * nm * __builtin_amdgcn_rcpf(nm + 2.f);
}
__device__ __forceinline__ f32x2 splat2(float v) { return (f32x2){v, v}; }
// deg-11 truncated Chebyshev of f(c)=e^{1-acos(c)/pi}, evaluated on float2
// pairs so the backend emits v_pk_fma_f32 / v_pk_min/max_f32 (packed fp32).
// Both sweeps share it, so P/rowsum systematics cancel.
__device__ __forceinline__ f32x2 fexp_poly2(f32x2 c) {
    c = __builtin_elementwise_min(
            __builtin_elementwise_max(c, splat2(-0.999999f)), splat2(0.999999f));
    f32x2 r = __builtin_elementwise_fma(splat2(6.3713280f), c, splat2(1.7809920f));
    r = __builtin_elementwise_fma(r, c, splat2(-15.1427584f));
    r = __builtin_elementwise_fma(r, c, splat2(-3.7571968f));
    r = __builtin_elementwise_fma(r, c, splat2(13.1518784f));
    r = __builtin_elementwise_fma(r, c, splat2(2.8140000f));
    r = __builtin_elementwise_fma(r, c, splat2(-4.8903712f));
    r = __builtin_elementwise_fma(r, c, splat2(-0.8122592f));
    r = __builtin_elementwise_fma(r, c, splat2(0.8441120f));
    r = __builtin_elementwise_fma(r, c, splat2(0.1705120f));
    r = __builtin_elementwise_fma(r, c, splat2(0.4936541f));
    r = __builtin_elementwise_fma(r, c, splat2(1.6473155f));
    return r;
}

// ---------- Kernel 1: grouped conv + BN + mish (+normalize/pack), split ----
// blocks 0..255: q | 256..511: k | 512..767: v | 768..831: f_w -> bf16.
// Split q/k/v to 3x the blocks (norms only need all 32 channels per tensor).
__global__ __launch_bounds__(256) void qkvpack_kernel(
    const float* __restrict__ x,
    const float* __restrict__ qw, const float* __restrict__ qb2,
    const float* __restrict__ qs, const float* __restrict__ qbeta,
    const float* __restrict__ kw, const float* __restrict__ kb2,
    const float* __restrict__ ks, const float* __restrict__ kbeta,
    const float* __restrict__ vw, const float* __restrict__ vb2,
    const float* __restrict__ vs, const float* __restrict__ vbeta,
    uint4* __restrict__ qpk, uint4* __restrict__ kpk, u16* __restrict__ vbf,
    const float* __restrict__ fw, u16* __restrict__ wbf)
{
    int blk = blockIdx.x;
    if (blk >= 768) {               // f_w -> bf16
        int id = (blk - 768) * 1024 + threadIdx.x;
#pragma unroll
        for (int j = 0; j < 4; ++j) { int p = id + j * 256; wbf[p] = (u16)bf16r(fw[p]); }
        return;
    }
    int type = blk >> 8;            // 0=q, 1=k, 2=v
    int sub = blk & 255;
    int nt = sub & 3, g = (sub >> 2) & 7, b = sub >> 5;
    int n = nt * 256 + threadIdx.x;
    int bh = b * 8 + g;
    const float* xp = x + ((size_t)b * C_ + g * 32) * N_ + n;
    float xv[32];
#pragma unroll
    for (int i = 0; i < 32; ++i) xv[i] = xp[(size_t)i * N_];

    const float *w, *bb, *sc, *bt;
    if (type == 0)      { w = qw; bb = qb2; sc = qs; bt = qbeta; }
    else if (type == 1) { w = kw; bb = kb2; sc = ks; bt = kbeta; }
    else                { w = vw; bb = vb2; sc = vs; bt = vbeta; }

    float y[32];
#pragma unroll
    for (int co = 0; co < 32; ++co) {
        int cg = g * 32 + co;
        float acc = 0.f;
#pragma unroll
        for (int i = 0; i < 32; ++i)
            acc = fmaf(xv[i], w[cg * 32 + i], acc);
        // INV_TEMP omitted for q: normalized below, scale cancels in cosine
        y[co] = mish_fast(sc[cg] * (acc + bb[cg]) + bt[cg]);
    }

    if (type == 2) {                // v: bf16 [bh][d][n]
#pragma unroll
        for (int co = 0; co < 32; ++co)
            vbf[((size_t)bh * 32 + co) * N_ + n] = (u16)bf16r(y[co]);
        return;
    }
    float s2 = 0.f;
#pragma unroll
    for (int d = 0; d < 32; ++d) s2 = fmaf(y[d], y[d], s2);
    float inv = __builtin_amdgcn_rsqf(fmaxf(s2, 1e-24f));
    u32 wp[16];
#pragma unroll
    for (int d = 0; d < 16; ++d)
        wp[d] = bf16r(y[2 * d] * inv) | (bf16r(y[2 * d + 1] * inv) << 16);
    uint4* dst = (type == 0 ? qpk : kpk) + ((size_t)bh * N_ + n) * 4;
#pragma unroll
    for (int j = 0; j < 4; ++j)
        dst[j] = make_uint4(wp[4 * j], wp[4 * j + 1], wp[4 * j + 2], wp[4 * j + 3]);
}

// ---------------- Kernel 2: attention (chunked, packed-f32 poly) -----------
// Block = (bh, 64-row itile), 4 waves x 16 rows. m in 8 chunks of 128.
// 37 KB LDS -> 4 blocks/CU. Q frag in regs; K/V staged per chunk via
// global_load_lds. Sweep 1: rowsums. Sweep 2: P(raw), am, PV; rinv deferred.
__global__ __launch_bounds__(256) void attn_kernel(
    const u16* __restrict__ qpk, const u16* __restrict__ kpk,
    const u16* __restrict__ vbf,
    u16* __restrict__ aout_bt, float* __restrict__ ampart)
{
    __shared__ __align__(16) u16 Kc[4][128][8];     // 8 KB  [dchunk][m][8]
    __shared__ __align__(16) u16 Vc[32][128];       // 8 KB  [d][m] granule-swz
    __shared__ __align__(16) u16 Ps[4][16 * 136];   // 17 KB, rows padded 272B
    __shared__ __align__(16) float amW[N_];         // 4 KB

    const int tid  = threadIdx.x;
    const int wave = tid >> 6, lane = tid & 63;
    const int l15 = lane & 15, lg = lane >> 4;
    const int blk = blockIdx.x;             // bh*16 + itile
    const int itile = blk & 15, bh = blk >> 4;
    const int h = bh & 7, bidx = bh >> 3;
    const int i0 = itile * 64;

    const char* ksrc = (const char*)(kpk + (size_t)bh * N_ * 32);
    const char* vsrc = (const char*)(vbf + (size_t)bh * 32 * N_);
    const char* qsrc = (const char*)(qpk + (size_t)bh * N_ * 32);

    for (int j = tid; j < N_; j += 256) amW[j] = 0.f;

    // Q frag: row = i0 + wave*16 + l15, d-chunk lg (held for whole kernel)
    bf16x8 aq = *(const bf16x8*)(qsrc + (size_t)(i0 + wave * 16 + l15) * 64 + lg * 16);

    const char* kfb = (const char*)Kc + lg * 2048 + l15 * 16;

    // ================= sweep 1: rowsums =================
    f32x2 rsL = {0.f, 0.f}, rsH = {0.f, 0.f};
    for (int ch = 0; ch < 8; ++ch) {
        int m0 = ch * 128;
        __syncthreads();
#pragma unroll
        for (int p = 0; p < 2; ++p) {
            int gi = p * 256 + wave * 64 + lane;
            int j = gi >> 7, m = gi & 127;
            __builtin_amdgcn_global_load_lds(
                (const AS1 void*)(ksrc + (size_t)(m0 + m) * 64 + j * 16),
                (AS3 void*)((char*)Kc + ((p * 256 + wave * 64) << 4)), 16, 0, 0);
        }
        __syncthreads();
#pragma unroll
        for (int t = 0; t < 8; ++t) {
            bf16x8 bk = *(const bf16x8*)(kfb + t * 256);
            f32x4 cf = {0.f, 0.f, 0.f, 0.f};
            cf = mfma16(aq, bk, cf);
            rsL += fexp_poly2((f32x2){cf[0], cf[1]});
            rsH += fexp_poly2((f32x2){cf[2], cf[3]});
        }
    }
    float rinv[4];
    {
        float rr[4] = {rsL.x, rsL.y, rsH.x, rsH.y};
#pragma unroll
        for (int r = 0; r < 4; ++r) {
            float s = rr[r];
            s += __shfl_xor(s, 1); s += __shfl_xor(s, 2);
            s += __shfl_xor(s, 4); s += __shfl_xor(s, 8);
            rinv[r] = __builtin_amdgcn_rcpf(s);
        }
    }
    f32x2 rinvL = {rinv[0], rinv[1]}, rinvH = {rinv[2], rinv[3]};

    // ================= sweep 2: P(raw), am, PV =================
    f32x4 o0 = {0.f, 0.f, 0.f, 0.f}, o1 = {0.f, 0.f, 0.f, 0.f};
    char*       psw = (char*)&Ps[wave][0] + lg * 1088 + l15 * 2;
    const char* pab = (const char*)&Ps[wave][0] + l15 * 272 + lg * 16;
    const char* vfb = (const char*)Vc + l15 * 256;
    const int   vkey = l15 & 7;

    for (int ch = 0; ch < 8; ++ch) {
        int m0 = ch * 128;
        __syncthreads();
#pragma unroll
        for (int p = 0; p < 2; ++p) {
            int gi = p * 256 + wave * 64 + lane;
            int j = gi >> 7, m = gi & 127;
            __builtin_amdgcn_global_load_lds(
                (const AS1 void*)(ksrc + (size_t)(m0 + m) * 64 + j * 16),
                (AS3 void*)((char*)Kc + ((p * 256 + wave * 64) << 4)), 16, 0, 0);
        }
#pragma unroll
        for (int p = 0; p < 2; ++p) {
            int gi = p * 256 + wave * 64 + lane;
            int d = gi >> 4, gm = gi & 15;
            __builtin_amdgcn_global_load_lds(
                (const AS1 void*)(vsrc + (size_t)d * 2048 + m0 * 2 + ((gm ^ (d & 7)) << 4)),
                (AS3 void*)((char*)Vc + ((p * 256 + wave * 64) << 4)), 16, 0, 0);
        }
        __syncthreads();

#pragma unroll
        for (int t = 0; t < 8; ++t) {
            bf16x8 bk = *(const bf16x8*)(kfb + t * 256);
            f32x4 cf = {0.f, 0.f, 0.f, 0.f};
            cf = mfma16(aq, bk, cf);
            f32x2 fL = fexp_poly2((f32x2){cf[0], cf[1]});
            f32x2 fH = fexp_poly2((f32x2){cf[2], cf[3]});
            *(u16*)(psw + 0 * 272 + t * 32) = (u16)bf16r(fL.x);
            *(u16*)(psw + 1 * 272 + t * 32) = (u16)bf16r(fL.y);
            *(u16*)(psw + 2 * 272 + t * 32) = (u16)bf16r(fH.x);
            *(u16*)(psw + 3 * 272 + t * 32) = (u16)bf16r(fH.y);
            f32x2 cs2 = fL * rinvL;
            cs2 = __builtin_elementwise_fma(fH, rinvH, cs2);
            float csum = cs2.x + cs2.y;
            csum += __shfl_xor(csum, 16);
            csum += __shfl_xor(csum, 32);
            if (lane < 16) atomicAdd(&amW[m0 + t * 16 + l15], csum);
        }
        asm volatile("s_waitcnt lgkmcnt(0)" ::: "memory");
        __builtin_amdgcn_sched_barrier(0);
#pragma unroll
        for (int kss = 0; kss < 4; ++kss) {
            bf16x8 pa = *(const bf16x8*)(pab + kss * 64);
            const char* va = vfb + (((kss * 4 + lg) ^ vkey) << 4);
            bf16x8 v0 = *(const bf16x8*)va;
            bf16x8 v1 = *(const bf16x8*)(va + 4096);      // d = 16 + l15
            o0 = mfma16(pa, v0, o0);
            o1 = mfma16(pa, v1, o1);
        }
    }
    __syncthreads();   // amW atomics done; Ps free for reuse

    // ---- epilogue: scale by rinv, transpose via LDS, store bf16 [b][n][c] ----
    {
        u16* oT = (u16*)Ps;                    // [64 rows][40 u16] (80B rows)
#pragma unroll
        for (int r = 0; r < 4; ++r) {
            int irow = wave * 16 + lg * 4 + r;
            oT[irow * 40 + l15]      = (u16)bf16r(o0[r] * rinv[r]);
            oT[irow * 40 + 16 + l15] = (u16)bf16r(o1[r] * rinv[r]);
        }
    }
    __syncthreads();
    {
        const u16* oT = (const u16*)Ps;
        int row = tid >> 2, c4 = tid & 3;
        uint4 val = *(const uint4*)((const char*)oT + row * 80 + c4 * 16);
        int n = i0 + row;
        int g = h * 4 + c4;
        size_t dst = ((size_t)(bidx * N_ + n) << 9) + ((size_t)((g ^ (row & 7)) << 4));
        *(uint4*)((char*)aout_bt + dst) = val;
    }
#pragma unroll
    for (int j2 = 0; j2 < 4; ++j2)
        ampart[(size_t)blk * N_ + tid + 256 * j2] = amW[tid + 256 * j2];
}

// ---------- Kernel 3: fconv (MFMA) + mish + residual; blocks 256..263: am --
__global__ __launch_bounds__(256) void fconv_kernel(
    const u16* __restrict__ aout_bt, const u16* __restrict__ wbf,
    const float* __restrict__ x,
    const float* __restrict__ fs, const float* __restrict__ fb,
    const float* __restrict__ fbeta, float* __restrict__ y,
    const float* __restrict__ ampart, float* __restrict__ outAm)
{
    __shared__ __align__(16) u16 As[32 * 256];   // 16 KB [n][c] swizzled
    __shared__ float rmn[256], rmx[256];
    const int tid = threadIdx.x;

    if (blockIdx.x >= 256) {       // ---- attention-map reduce + normalize ----
        int b = blockIdx.x - 256;
        const float* base = ampart + (size_t)b * 128 * N_;
        float s[4] = {0.f, 0.f, 0.f, 0.f};
        for (int p = 0; p < 128; ++p) {
#pragma unroll
            for (int c2 = 0; c2 < 4; ++c2)
                s[c2] += base[(size_t)p * N_ + tid + 256 * c2];
        }
        float mn = fminf(fminf(s[0], s[1]), fminf(s[2], s[3]));
        float mx = fmaxf(fmaxf(s[0], s[1]), fmaxf(s[2], s[3]));
        rmn[tid] = mn; rmx[tid] = mx;
        __syncthreads();
        for (int off = 128; off >= 1; off >>= 1) {
            if (tid < off) {
                rmn[tid] = fminf(rmn[tid], rmn[tid + off]);
                rmx[tid] = fmaxf(rmx[tid], rmx[tid + off]);
            }
            __syncthreads();
        }
        mn = rmn[0]; mx = rmx[0];
        float inv = 1.f / (mx - mn);
#pragma unroll
        for (int c2 = 0; c2 < 4; ++c2)
            outAm[(size_t)b * N_ + tid + 256 * c2] = (s[c2] - mn) * inv;
        return;
    }

    const int wave = tid >> 6, lane = tid & 63;
    const int l15 = lane & 15, lg = lane >> 4;
    const int b  = blockIdx.x >> 5;
    const int n0 = (blockIdx.x & 31) * 32;

    const char* asrc = (const char*)aout_bt + ((size_t)(b * N_ + n0) << 9);
#pragma unroll
    for (int p = 0; p < 4; ++p) {
        int g = p * 256 + wave * 64 + lane;
        __builtin_amdgcn_global_load_lds(
            (const AS1 void*)(asrc + g * 16),
            (AS3 void*)((char*)As + ((p * 256 + wave * 64) << 4)), 16, 0, 0);
    }
    __syncthreads();

    f32x4 acc[4][2];
#pragma unroll
    for (int f = 0; f < 4; ++f)
#pragma unroll
        for (int fn = 0; fn < 2; ++fn) acc[f][fn] = (f32x4){0.f, 0.f, 0.f, 0.f};

    const int cobase = wave * 64;
#pragma unroll
    for (int kk = 0; kk < 8; ++kk) {
        bf16x8 af[2];
#pragma unroll
        for (int fn = 0; fn < 2; ++fn) {
            int nf = fn * 16 + l15;
            af[fn] = *(const bf16x8*)((const char*)As + nf * 512 +
                                      (((kk * 4 + lg) ^ (nf & 7)) << 4));
        }
#pragma unroll
        for (int f = 0; f < 4; ++f) {
            bf16x8 wf = *(const bf16x8*)(wbf + (size_t)(cobase + f * 16 + l15) * 256 + kk * 32 + lg * 8);
            acc[f][0] = mfma16(wf, af[0], acc[f][0]);
            acc[f][1] = mfma16(wf, af[1], acc[f][1]);
        }
    }

#pragma unroll
    for (int f = 0; f < 4; ++f) {
#pragma unroll
        for (int r = 0; r < 4; ++r) {
            int co = cobase + f * 16 + lg * 4 + r;
            float sc = fs[co], bb = fb[co], bt = fbeta[co];
#pragma unroll
            for (int fn = 0; fn < 2; ++fn) {
                int n = n0 + fn * 16 + l15;
                size_t oid = ((size_t)(b * C_ + co) << 10) + n;
                y[oid] = mish_fast(sc * (acc[f][fn][r] + bb) + bt) + x[oid];
            }
        }
    }
}

extern "C" void kernel_launch(void* const* d_in, const int* in_sizes, int n_in,
                              void* d_out, int out_size, void* d_ws, size_t ws_size,
                              hipStream_t stream)
{
    const float* x     = (const float*)d_in[0];
    const float* q_w   = (const float*)d_in[1];
    const float* q_b   = (const float*)d_in[2];
    const float* q_s   = (const float*)d_in[3];
    const float* q_be  = (const float*)d_in[4];
    const float* k_w   = (const float*)d_in[5];
    const float* k_b   = (const float*)d_in[6];
    const float* k_s   = (const float*)d_in[7];
    const float* k_be  = (const float*)d_in[8];
    const float* v_w   = (const float*)d_in[9];
    const float* v_b   = (const float*)d_in[10];
    const float* v_s   = (const float*)d_in[11];
    const float* v_be  = (const float*)d_in[12];
    const float* f_w   = (const float*)d_in[13];
    const float* f_b   = (const float*)d_in[14];
    const float* f_s   = (const float*)d_in[15];
    const float* f_be  = (const float*)d_in[16];

    float* y_out  = (float*)d_out;                        // (8,256,32,32)
    float* am_out = (float*)d_out + (size_t)B_ * C_ * N_; // (8,32,32)

    char* w = (char*)d_ws;
    u16*   qpk     = (u16*)w;    w += (size_t)B_ * NH_ * N_ * 64;    // 4 MB
    u16*   kpk     = (u16*)w;    w += (size_t)B_ * NH_ * N_ * 64;    // 4 MB
    u16*   vbf     = (u16*)w;    w += (size_t)B_ * C_ * N_ * 2;      // 4 MB
    u16*   aout_bt = (u16*)w;    w += (size_t)B_ * N_ * C_ * 2;      // 4 MB
    float* ampart  = (float*)w;  w += (size_t)B_ * NH_ * 16 * N_ * 4;// 4 MB
    u16*   wbf     = (u16*)w;                                        // 128 KB

    qkvpack_kernel<<<832, 256, 0, stream>>>(
        x, q_w, q_b, q_s, q_be, k_w, k_b, k_s, k_be,
        v_w, v_b, v_s, v_be, (uint4*)qpk, (uint4*)kpk, vbf, f_w, wbf);

    attn_kernel<<<B_ * NH_ * 16, 256, 0, stream>>>(
        qpk, kpk, vbf, aout_bt, ampart);

    fconv_kernel<<<264, 256, 0, stream>>>(
        aout_bt, wbf, x, f_s, f_b, f_be, y_out, ampart, am_out);
}